// Round 3
// baseline (459.220 us; speedup 1.0000x reference)
//
#include <hip/hip_runtime.h>

#define SEQ 1024
#define BATCH 512
#define NTAGS 64

typedef float v2f __attribute__((ext_vector_type(2)));

// Compiler-only ordering fence for wave-synchronous LDS use (single wave,
// in-order DS pipe -> no s_barrier / vmcnt(0) drain needed).
#define WAVE_FENCE() asm volatile("" ::: "memory")

// Two chains per wave: lanes 0..31 = chain (2*blk), lanes 32..63 = chain
// (2*blk+1). Lane l owns output tags jl=(l&31) and jh=jl+32 of its chain.
// Linear-space forward recurrence per chain:
//   beta'_j = (sum_i beta_i * expT[i][j]) * exp(em[t,j])
// with group-of-4 stale renormalization (divide by 2-step-old beta_0 folded
// into the exp(em) factor). The 16 broadcast ds_read_b128 per step now feed
// BOTH chains (2-address broadcast = conflict-free), halving per-chain cost.
__global__ __launch_bounds__(64, 1)
void crf_kernel(const float* __restrict__ em,
                const int* __restrict__ tags,
                const int* __restrict__ mask,
                const float* __restrict__ startT,
                const float* __restrict__ endT,
                const float* __restrict__ trans,
                float* __restrict__ out)
{
    const int l     = threadIdx.x;
    const int half  = l >> 5;
    const int jl    = l & 31;
    const int jh    = jl + 32;
    const int hbase = half << 5;                 // first lane of my half
    const int b     = blockIdx.x * 2 + half;     // my chain

    __shared__ float trans_sh[NTAGS * NTAGS];
    __shared__ __align__(16) float beta_sh[2 * NTAGS];

    // expT columns for my two output tags (128 VGPRs, packed for pk_fma);
    // raw trans into LDS for numerator lookups (lower half covers all cols).
    v2f colL[NTAGS / 2], colH[NTAGS / 2];
#pragma unroll
    for (int i = 0; i < NTAGS; i += 2) {
        float tl0 = trans[(i + 0) * NTAGS + jl];
        float tl1 = trans[(i + 1) * NTAGS + jl];
        float th0 = trans[(i + 0) * NTAGS + jh];
        float th1 = trans[(i + 1) * NTAGS + jh];
        if (half == 0) {
            trans_sh[(i + 0) * NTAGS + jl] = tl0;
            trans_sh[(i + 1) * NTAGS + jl] = tl1;
            trans_sh[(i + 0) * NTAGS + jh] = th0;
            trans_sh[(i + 1) * NTAGS + jh] = th1;
        }
        v2f cl; cl.x = __expf(tl0); cl.y = __expf(tl1); colL[i / 2] = cl;
        v2f ch; ch.x = __expf(th0); ch.y = __expf(th1); colH[i / 2] = ch;
    }

    const float eendL = __expf(endT[jl]);
    const float eendH = __expf(endT[jh]);

    // chain length (prefix mask column sum), then wave max
    int lsum = 0;
#pragma unroll
    for (int k = 0; k < SEQ / 32; ++k)
        lsum += mask[(k * 32 + jl) * BATCH + b];
#pragma unroll
    for (int off = 16; off > 0; off >>= 1)
        lsum += __shfl_xor(lsum, off);
    const int Lc   = lsum;                       // uniform within half
    const int Lmax = max(Lc, __shfl_xor(Lc, 32));

    // ---- t = 0 ----
    float emL = em[(size_t)b * NTAGS + jl];
    float emH = em[(size_t)b * NTAGS + jh];
    float aL  = startT[jl] + emL;
    float aH  = startT[jh] + emH;
    float M     = __shfl(aL, hbase);             // alpha[tag 0] of my chain
    float betaL = __expf(aL - M);
    float betaH = __expf(aH - M);

    int   prev = tags[b];                        // uniform within half
    float num;
    {
        float g0 = __shfl(emL, hbase + (prev & 31));
        float g1 = __shfl(emH, hbase + (prev & 31));
        num = startT[prev] + ((prev >= 32) ? g1 : g0);
    }

    float* myrow = beta_sh + half * NTAGS;
    const float4* bv = (const float4*)myrow;

    WAVE_FENCE();

#define DOT2(SL, SH)                                                      \
    {                                                                     \
        WAVE_FENCE();                                                     \
        myrow[jl] = betaL;                                                \
        myrow[jh] = betaH;                                                \
        WAVE_FENCE();                                                     \
        v2f aL0 = {0.f,0.f}, aL1 = {0.f,0.f};                             \
        v2f aH0 = {0.f,0.f}, aH1 = {0.f,0.f};                             \
        _Pragma("unroll")                                                 \
        for (int i4 = 0; i4 < 16; ++i4) {                                 \
            float4 q = bv[i4];                                            \
            v2f p0; p0.x = q.x; p0.y = q.y;                               \
            v2f p1; p1.x = q.z; p1.y = q.w;                               \
            aL0 += p0 * colL[2 * i4 + 0];                                 \
            aL1 += p1 * colL[2 * i4 + 1];                                 \
            aH0 += p0 * colH[2 * i4 + 0];                                 \
            aH1 += p1 * colH[2 * i4 + 1];                                 \
        }                                                                 \
        v2f tL = aL0 + aL1; SL = tL.x + tL.y;                             \
        v2f tH = aH0 + aH1; SH = tH.x + tH.y;                             \
    }

    int t = 1;

    // distance-4 prefetch
    float emLc[4], emHc[4]; int tgc[4];
#pragma unroll
    for (int u = 0; u < 4; ++u) {
        int tt = min(t + u, SEQ - 1);
        emLc[u] = em[((size_t)tt * BATCH + b) * NTAGS + jl];
        emHc[u] = em[((size_t)tt * BATCH + b) * NTAGS + jh];
        tgc[u]  = tags[tt * BATCH + b];
    }

    while (t + 3 <= Lmax - 1) {
        float emLn[4], emHn[4]; int tgn[4];
#pragma unroll
        for (int u = 0; u < 4; ++u) {
            int tt = min(t + 4 + u, SEQ - 1);
            emLn[u] = em[((size_t)tt * BATCH + b) * NTAGS + jl];
            emHn[u] = em[((size_t)tt * BATCH + b) * NTAGS + jh];
            tgn[u]  = tags[tt * BATCH + b];
        }

        bool act0 = (t + 0) < Lc, act1 = (t + 1) < Lc;
        bool act2 = (t + 2) < Lc, act3 = (t + 3) < Lc;
        const bool full = act3;                  // prefix mask

        float eemL[4], eemH[4];
#pragma unroll
        for (int u = 0; u < 4; ++u) { eemL[u] = __expf(emLc[u]); eemH[u] = __expf(emHc[u]); }

        // numerator lookups (off critical path)
        float tr[4], ge[4];
        {
            int p = prev;
#pragma unroll
            for (int u = 0; u < 4; ++u) {
                tr[u] = trans_sh[p * NTAGS + tgc[u]];
                float g0 = __shfl(emLc[u], hbase + (tgc[u] & 31));
                float g1 = __shfl(emHc[u], hbase + (tgc[u] & 31));
                ge[u] = (tgc[u] >= 32) ? g1 : g0;
                p = tgc[u];
            }
        }

        float sL, sH;

        DOT2(sL, sH);
        betaL = act0 ? sL * eemL[0] : betaL;
        betaH = act0 ? sH * eemH[0] : betaH;

        DOT2(sL, sH);
        betaL = act1 ? sL * eemL[1] : betaL;
        betaH = act1 ? sH * eemH[1] : betaH;
        float rs = __shfl(betaL, hbase);         // stale scale (tag 0)

        DOT2(sL, sH);
        betaL = act2 ? sL * eemL[2] : betaL;
        betaH = act2 ? sH * eemH[2] : betaH;
        float rinv = full ? 1.0f / rs : 1.0f;    // off-path
        float lrs  = full ? __logf(rs) : 0.0f;

        DOT2(sL, sH);
        betaL = act3 ? sL * (eemL[3] * rinv) : betaL;
        betaH = act3 ? sH * (eemH[3] * rinv) : betaH;
        M += lrs;

        num += (act0 ? tr[0] + ge[0] : 0.f) + (act1 ? tr[1] + ge[1] : 0.f)
             + (act2 ? tr[2] + ge[2] : 0.f) + (act3 ? tr[3] + ge[3] : 0.f);
        prev = act0 ? tgc[0] : prev;
        prev = act1 ? tgc[1] : prev;
        prev = act2 ? tgc[2] : prev;
        prev = act3 ? tgc[3] : prev;

#pragma unroll
        for (int u = 0; u < 4; ++u) { emLc[u] = emLn[u]; emHc[u] = emHn[u]; tgc[u] = tgn[u]; }
        t += 4;
    }

    // tail (<=3 steps), per-step renorm, per-chain predication
    for (; t <= Lmax - 1; ++t) {
        bool act = t < Lc;
        float emLt = em[((size_t)t * BATCH + b) * NTAGS + jl];
        float emHt = em[((size_t)t * BATCH + b) * NTAGS + jh];
        int   cur  = tags[t * BATCH + b];
        float trv  = trans_sh[prev * NTAGS + cur];
        float g0 = __shfl(emLt, hbase + (cur & 31));
        float g1 = __shfl(emHt, hbase + (cur & 31));
        num += act ? trv + ((cur >= 32) ? g1 : g0) : 0.f;
        prev = act ? cur : prev;

        float sL, sH;
        DOT2(sL, sH);
        float nbL = sL * __expf(emLt);
        float nbH = sH * __expf(emHt);
        float rsv = __shfl(nbL, hbase);
        rsv = act ? rsv : 1.0f;
        float ri = 1.0f / rsv;
        betaL = act ? nbL * ri : betaL;
        betaH = act ? nbH * ri : betaH;
        M += __logf(rsv);
    }

    num += endT[prev];

    // denominator = M + log(sum_j beta_j * exp(end_j)) per chain
    float v = betaL * eendL + betaH * eendH;
#pragma unroll
    for (int off = 16; off > 0; off >>= 1)
        v += __shfl_xor(v, off);
    float denom = M + __logf(v);

    if (jl == 0)
        atomicAdd(out, num - denom);
}

extern "C" void kernel_launch(void* const* d_in, const int* in_sizes, int n_in,
                              void* d_out, int out_size, void* d_ws, size_t ws_size,
                              hipStream_t stream)
{
    const float* em     = (const float*)d_in[0];
    const int*   tags   = (const int*)d_in[1];
    const int*   mask   = (const int*)d_in[2];
    const float* startT = (const float*)d_in[3];
    const float* endT   = (const float*)d_in[4];
    const float* trans  = (const float*)d_in[5];
    float*       out    = (float*)d_out;

    hipMemsetAsync(out, 0, sizeof(float) * out_size, stream);
    crf_kernel<<<BATCH / 2, 64, 0, stream>>>(em, tags, mask, startT, endT, trans, out);
}